// Round 9
// baseline (78.472 us; speedup 1.0000x reference)
//
#include <hip/hip_runtime.h>
#include <cstdint>
#include <cstddef>

// VanillaRNN: B=4096, T=512, H=128, C=10
// Round 9: r8 algorithm (two-limb f16 MFMA transient + saturation lock +
// bitmask time-skip; t=0 specialized; W-convert overlapped; one-parity light
// writes). Three serial-chain cuts on the ~15 executed heavy steps:
//  - MFMA chain depth 4 -> 2: accumulators split kc{0,1}/kc{2,3} (6 chains
//    of 2 vs 3 of 4); ~2 MFMA latencies off the per-step chain. accWh
//    low-bit change ~1e-6 rel (flip window ~2e-2 -> harmless).
//  - saturated path: flags computed+written right after the sat ballot
//    (hv = copysign available immediately; no f16-conversion wait on the
//    inter-wave chain the barrier releases on).
//  - saturated limb pack is pure bit ops: limb1 = 0x3C00|sign, limb2 = 0
//    (bit-identical: (_Float16)(+-1.0f) = +-1.0h, residual exactly 0).
// Skip validity (unchanged): stable (h==h_prev, all |pre|>10 => h=+-1 exact,
// accWh current) => step t identity iff |x_t[b]| < X_b,
// X_b = min_i (c_i h_i - 10.5)/|Whx_i|; ballot-all-sat path == executing.

#define TLEN 512
#define HDIM 128
#define NCLS 10
#define HS   136                   // h column stride in f16 (272 B, 16B-aligned)
#define LIMBSTRIDE (16 * HS)
#define PARSTRIDE  (2 * LIMBSTRIDE)
#define XSF  516                   // x stage row stride in floats (2-way banks)

typedef _Float16 f16x8 __attribute__((ext_vector_type(8)));
typedef float    f32x4 __attribute__((ext_vector_type(4)));

union PK4 { _Float16 h[4]; uint2 u; };

__device__ __forceinline__ float tanh_fast(float x) {
    // tanh(x) = 1 - 2/(e^{2x}+1); exact +-1.0f for |x|>10 after fp32 rounding
    float e = __expf(2.0f * x);
    return 1.0f - 2.0f * __builtin_amdgcn_rcpf(e + 1.0f);
}

__global__ __launch_bounds__(256, 1) void rnn_kernel(
    const float* __restrict__ x,    // [B,T]
    const float* __restrict__ Whx,  // [H]
    const float* __restrict__ Whh,  // [H,H]
    const float* __restrict__ Wph,  // [C,H]
    const float* __restrict__ bh,   // [H]
    const float* __restrict__ bp,   // [C]
    float* __restrict__ out)        // [B,C]
{
    __shared__ _Float16 hbuf[2 * PARSTRIDE];   // [parity][limb][col][k]; NO init
    __shared__ float    xs[16 * XSF];          // [col][t]
    __shared__ unsigned flagw[2];              // byte w: bit0 changed, bit1 sat
    __shared__ unsigned Xs[16];
    __shared__ unsigned vmask[16] __attribute__((aligned(16)));

    const int tid  = threadIdx.x;
    const int w    = tid >> 6;     // wave 0..3: rows [32w, 32w+32)
    const int lane = tid & 63;
    const int n    = lane & 15;    // MFMA col (batch)
    const int q    = lane >> 4;    // quad
    const int blk  = blockIdx.x;

    // ---- x load (coalesced float4) and stage to LDS ----
    const int xrow = tid >> 4, xsl = tid & 15;
    {
        const float* xp = &x[(size_t)(blk * 16 + xrow) * TLEN];
        f32x4 xr0[8];
        #pragma unroll
        for (int j = 0; j < 8; ++j)
            xr0[j] = *(const f32x4*)&xp[64 * j + 4 * xsl];
        #pragma unroll
        for (int j = 0; j < 8; ++j)
            *(f32x4*)&xs[xrow * XSF + 64 * j + 4 * xsl] = xr0[j];
    }

    // ---- issue W_hh loads early (f32 regs); convert after step 0 ----
    float wtmp[2][4][8];
    #pragma unroll
    for (int u = 0; u < 2; ++u)
        #pragma unroll
        for (int kc = 0; kc < 4; ++kc) {
            const int row = 32 * w + 16 * u + n;
            const float* wp = &Whh[row * HDIM + 32 * kc + 8 * q];
            const float4 f0 = *(const float4*)&wp[0];
            const float4 f1 = *(const float4*)&wp[4];
            wtmp[u][kc][0] = f0.x; wtmp[u][kc][1] = f0.y;
            wtmp[u][kc][2] = f0.z; wtmp[u][kc][3] = f0.w;
            wtmp[u][kc][4] = f1.x; wtmp[u][kc][5] = f1.y;
            wtmp[u][kc][6] = f1.z; wtmp[u][kc][7] = f1.w;
        }

    // per-lane row constants: acc element (u,r) -> row 32w + 16u + 4q + r
    float wx[8], bb[8];
    #pragma unroll
    for (int u = 0; u < 2; ++u)
        #pragma unroll
        for (int r = 0; r < 4; ++r) {
            const int row = 32 * w + 16 * u + 4 * q + r;
            wx[4 * u + r] = Whx[row];
            bb[4 * u + r] = bh[row];
        }

    __syncthreads();               // xs visible

    float accWh[8], h_prev[8], hv[8];
    #pragma unroll
    for (int i = 0; i < 8; ++i) { accWh[i] = 0.0f; h_prev[i] = 0.0f; }

    auto writeLimbs = [&](int par) {                 // generic (transient) pack
        #pragma unroll
        for (int u = 0; u < 2; ++u) {
            PK4 p1, p2;
            #pragma unroll
            for (int r = 0; r < 4; ++r) {
                const float v = hv[4 * u + r];
                const _Float16 hh = (_Float16)v;
                p1.h[r] = hh;
                p2.h[r] = (_Float16)((v - (float)hh) * 2048.0f);
            }
            const int kb = 32 * w + 16 * u + 4 * q;
            *(uint2*)&hbuf[par * PARSTRIDE +              n * HS + kb] = p1.u;
            *(uint2*)&hbuf[par * PARSTRIDE + LIMBSTRIDE + n * HS + kb] = p2.u;
        }
    };
    auto writeSat = [&](int par) {                   // h = +-1 exactly
        #pragma unroll
        for (int u = 0; u < 2; ++u) {
            uint2 pk;
            const unsigned s0 = (__float_as_uint(hv[4 * u + 0]) >> 16) & 0x8000u;
            const unsigned s1 = (__float_as_uint(hv[4 * u + 1]) >> 16) & 0x8000u;
            const unsigned s2 = (__float_as_uint(hv[4 * u + 2]) >> 16) & 0x8000u;
            const unsigned s3 = (__float_as_uint(hv[4 * u + 3]) >> 16) & 0x8000u;
            pk.x = (0x3C00u | s0) | ((0x3C00u | s1) << 16);
            pk.y = (0x3C00u | s2) | ((0x3C00u | s3) << 16);
            const int kb = 32 * w + 16 * u + 4 * q;
            *(uint2*)&hbuf[par * PARSTRIDE +              n * HS + kb] = pk;
            *(uint2*)&hbuf[par * PARSTRIDE + LIMBSTRIDE + n * HS + kb] = (uint2){0u, 0u};
        }
    };

    // ---- step 0: h = 0 -> pre = wx*x0 + bb; no flags, no B, no MFMA ----
    {
        const float xt0 = xs[n * XSF + 0];
        float pre[8];
        #pragma unroll
        for (int i = 0; i < 8; ++i) pre[i] = fmaf(wx[i], xt0, bb[i]);
        bool sat = true;
        #pragma unroll
        for (int i = 0; i < 8; ++i) sat = sat && (fabsf(pre[i]) > 10.0f);
        const bool wave_sat = (__ballot(sat) == ~0ull);
        if (wave_sat) {
            #pragma unroll
            for (int i = 0; i < 8; ++i) hv[i] = copysignf(1.0f, pre[i]);
        } else {
            #pragma unroll
            for (int i = 0; i < 8; ++i) hv[i] = tanh_fast(pre[i]);
        }
        bool eq = true;
        #pragma unroll
        for (int i = 0; i < 8; ++i) eq = eq && (hv[i] == 0.0f);
        const bool wave_changed = (__ballot(eq) != ~0ull);
        #pragma unroll
        for (int i = 0; i < 8; ++i) h_prev[i] = hv[i];
        if (wave_sat) writeSat(1); else writeLimbs(1);
        if (lane == 0)
            ((unsigned char*)&flagw[1])[w] =
                (unsigned char)((wave_changed ? 1u : 0u) | (wave_sat ? 2u : 0u));
    }

    // ---- W-limb conversion (VALU; overlaps step-0 LDS drain) ----
    f16x8 w1[2][4], w2[2][4];
    #pragma unroll
    for (int u = 0; u < 2; ++u)
        #pragma unroll
        for (int kc = 0; kc < 4; ++kc)
            #pragma unroll
            for (int j = 0; j < 8; ++j) {
                const float v = wtmp[u][kc][j];
                const _Float16 a = (_Float16)v;
                w1[u][kc][j] = a;
                w2[u][kc][j] = (_Float16)((v - (float)a) * 2048.0f);
            }

    __syncthreads();               // step-0 h + flags visible

    int p  = 1;                    // parity of hbuf holding current h
    int sp = 1;                    // flag-word parity
    bool maskvalid = false;
    unsigned vm[16];

    int t = 1;
    while (t < TLEN) {
        const unsigned fw = flagw[sp];                 // issued first
        // unconditional B-fragment prefetch from hbuf[p] (current h);
        // latency overlaps flag wait; values discarded on light steps
        const _Float16* hb = &hbuf[p * PARSTRIDE];
        f16x8 b1[4], b2[4];
        #pragma unroll
        for (int kc = 0; kc < 4; ++kc) {
            b1[kc] = *(const f16x8*)&hb[             n * HS + 32 * kc + 8 * q];
            b2[kc] = *(const f16x8*)&hb[LIMBSTRIDE + n * HS + 32 * kc + 8 * q];
        }

        const bool heavy  = (fw & 0x01010101u) != 0u;  // someone's h changed
        const bool allsat = (fw & 0x02020202u) == 0x02020202u;
        if (heavy) maskvalid = false;                  // block-uniform
        bool do_heavy = heavy;

        if (!heavy && allsat) {
            // ---- stable: h frozen at exact +-1, accWh current ----
            if (!maskvalid) {
                if (tid < 16) { Xs[tid] = 0x7f800000u; vmask[tid] = 0u; }
                float m8 = 3.0e38f;
                #pragma unroll
                for (int i = 0; i < 8; ++i) {
                    const float c  = accWh[i] + bb[i];
                    const float mi = (c * h_prev[i] - 10.5f) / fmaxf(fabsf(wx[i]), 1e-30f);
                    m8 = fminf(m8, mi);
                }
                m8 = fmaxf(m8, 0.0f);                  // nonneg: uint order ok
                __syncthreads();
                atomicMin(&Xs[n], __float_as_uint(m8));
                __syncthreads();
                const float Xc = __uint_as_float(Xs[xrow]);
                const float* xrp = &xs[xrow * XSF];
                #pragma unroll
                for (int j = 0; j < 8; ++j) {
                    unsigned nib = 0u;
                    #pragma unroll
                    for (int m = 0; m < 4; ++m)
                        if (fabsf(xrp[64 * j + 4 * xsl + m]) >= Xc) nib |= (1u << m);
                    if (nib) atomicOr(&vmask[2 * j + (xsl >> 3)], nib << (4 * (xsl & 7)));
                }
                __syncthreads();
                #pragma unroll
                for (int k = 0; k < 4; ++k) {
                    const uint4 v4 = *(const uint4*)&vmask[4 * k];
                    vm[4 * k] = v4.x; vm[4 * k + 1] = v4.y;
                    vm[4 * k + 2] = v4.z; vm[4 * k + 3] = v4.w;
                }
                maskvalid = true;
            }
            // next violation >= t (register ffs; block-uniform)
            int nt = TLEN;
            #pragma unroll
            for (int wd = 15; wd >= 0; --wd) {
                const int base = 32 * wd;
                unsigned mm = vm[wd];
                mm = (base + 31 < t) ? 0u
                   : ((base < t) ? (mm & ~((1u << (t - base)) - 1u)) : mm);
                if (mm) nt = base + __ffs(mm) - 1;
            }
            if (nt >= TLEN) break;        // identity to the end
            t = nt;                       // steps [t, nt) are identity
            do_heavy = false;             // accWh current; light step at nt
        }

        // ---- execute one step at time t ----
        const float xt = xs[n * XSF + t];

        if (do_heavy) {
            #pragma unroll
            for (int u = 0; u < 2; ++u) {
                f32x4 a0a = {0,0,0,0}, a0b = {0,0,0,0};
                f32x4 a1a = {0,0,0,0}, a1b = {0,0,0,0};
                f32x4 a1c = {0,0,0,0}, a1d = {0,0,0,0};
                #pragma unroll
                for (int kc = 0; kc < 2; ++kc) {
                    a0a = __builtin_amdgcn_mfma_f32_16x16x32_f16(w1[u][kc], b1[kc], a0a, 0, 0, 0);
                    a1a = __builtin_amdgcn_mfma_f32_16x16x32_f16(w1[u][kc], b2[kc], a1a, 0, 0, 0);
                    a1c = __builtin_amdgcn_mfma_f32_16x16x32_f16(w2[u][kc], b1[kc], a1c, 0, 0, 0);
                }
                #pragma unroll
                for (int kc = 2; kc < 4; ++kc) {
                    a0b = __builtin_amdgcn_mfma_f32_16x16x32_f16(w1[u][kc], b1[kc], a0b, 0, 0, 0);
                    a1b = __builtin_amdgcn_mfma_f32_16x16x32_f16(w1[u][kc], b2[kc], a1b, 0, 0, 0);
                    a1d = __builtin_amdgcn_mfma_f32_16x16x32_f16(w2[u][kc], b1[kc], a1d, 0, 0, 0);
                }
                #pragma unroll
                for (int r = 0; r < 4; ++r)
                    accWh[4 * u + r] =
                        fmaf((a1a[r] + a1c[r]) + (a1b[r] + a1d[r]), 0x1p-11f,
                             a0a[r] + a0b[r]);
            }
        }

        float pre[8];
        #pragma unroll
        for (int i = 0; i < 8; ++i)
            pre[i] = accWh[i] + fmaf(wx[i], xt, bb[i]);

        bool sat = true;
        #pragma unroll
        for (int i = 0; i < 8; ++i) sat = sat && (fabsf(pre[i]) > 10.0f);
        const bool wave_sat = (__ballot(sat) == ~0ull);

        if (wave_sat) {
            // hv available immediately -> flags off the chain first
            #pragma unroll
            for (int i = 0; i < 8; ++i) hv[i] = copysignf(1.0f, pre[i]);
            bool eq = true;
            #pragma unroll
            for (int i = 0; i < 8; ++i) eq = eq && (hv[i] == h_prev[i]);
            const bool wave_changed = (__ballot(eq) != ~0ull);
            if (lane == 0)
                ((unsigned char*)&flagw[sp ^ 1])[w] =
                    (unsigned char)((wave_changed ? 1u : 0u) | 2u);
            #pragma unroll
            for (int i = 0; i < 8; ++i) h_prev[i] = hv[i];
            if (do_heavy)            { writeSat(p ^ 1); p ^= 1; }
            else if (wave_changed)   writeSat(p);
        } else {
            #pragma unroll
            for (int i = 0; i < 8; ++i) hv[i] = tanh_fast(pre[i]);
            bool eq = true;
            #pragma unroll
            for (int i = 0; i < 8; ++i) eq = eq && (hv[i] == h_prev[i]);
            const bool wave_changed = (__ballot(eq) != ~0ull);
            if (lane == 0)
                ((unsigned char*)&flagw[sp ^ 1])[w] =
                    (unsigned char)(wave_changed ? 1u : 0u);
            #pragma unroll
            for (int i = 0; i < 8; ++i) h_prev[i] = hv[i];
            if (do_heavy)            { writeLimbs(p ^ 1); p ^= 1; }
            else if (wave_changed)   writeLimbs(p);
        }
        __syncthreads();
        sp ^= 1;
        ++t;
    }

    // ---- projection: out[b][co] = sum_i Wph[co][i]*h_T[i][b] + bp[co] ----
    if (tid < 16 * NCLS) {
        const int c  = tid / NCLS;
        const int co = tid - c * NCLS;
        const int base = p * PARSTRIDE + c * HS;
        float s = bp[co];
        #pragma unroll
        for (int kc = 0; kc < 16; ++kc) {
            const f16x8 v1 = *(const f16x8*)&hbuf[base + 8 * kc];
            const f16x8 v2 = *(const f16x8*)&hbuf[base + LIMBSTRIDE + 8 * kc];
            #pragma unroll
            for (int j = 0; j < 8; ++j)
                s = fmaf(Wph[co * HDIM + 8 * kc + j],
                         (float)v1[j] + (float)v2[j] * (1.0f / 2048.0f), s);
        }
        out[((size_t)blk * 16 + c) * NCLS + co] = s;
    }
}

extern "C" void kernel_launch(void* const* d_in, const int* in_sizes, int n_in,
                              void* d_out, int out_size, void* d_ws, size_t ws_size,
                              hipStream_t stream) {
    const float* x   = (const float*)d_in[0];  // [4096,512]
    const float* Whx = (const float*)d_in[1];  // [128,1]
    const float* Whh = (const float*)d_in[2];  // [128,128]
    const float* Wph = (const float*)d_in[3];  // [10,128]
    const float* bh  = (const float*)d_in[4];  // [128,1]
    const float* bp  = (const float*)d_in[5];  // [10,1]
    float* out = (float*)d_out;                // [4096,10]

    rnn_kernel<<<dim3(256), dim3(256), 0, stream>>>(x, Whx, Whh, Wph, bh, bp, out);
}